// Round 1
// baseline (859.430 us; speedup 1.0000x reference)
//
#include <hip/hip_runtime.h>
#include <math.h>

#define V 50257
#define B 64
#define HD 1024
#define LSRC 128

typedef float v4f __attribute__((ext_vector_type(4)));
typedef __bf16 v8bf __attribute__((ext_vector_type(8)));
typedef unsigned short v8us __attribute__((ext_vector_type(8)));

__device__ inline unsigned int pk_bf2(float x, float y) {
    // pack two f32 to bf16x2 by truncation (low = x, high = y)
    return (__float_as_uint(x) >> 16) | (__float_as_uint(y) & 0xffff0000u);
}

// ---------- 1. gather embedding + transpose h0 into cat1T/cat2T ----------
// cat1T[k][b], k<1024: emb, k>=1024: h0.  cat2T[k][b] k<1024: emb (ctx fills rest)
__global__ void k_prep(const int* __restrict__ idx, const float* __restrict__ hidden,
                       const float* __restrict__ emb, float* __restrict__ cat1T,
                       float* __restrict__ cat2T) {
    int i = blockIdx.x * 256 + threadIdx.x;   // 64*2048
    int b = i >> 11;
    int k = i & 2047;
    float v;
    if (k < 1024) {
        v = emb[(size_t)idx[b] * 1024 + k];
        cat2T[k * 64 + b] = v;
    } else {
        v = hidden[b * 1024 + (k - 1024)];
    }
    cat1T[k * 64 + b] = v;
}

// ---------- 2. attention logits + softmax ----------
__global__ void k_attnw(const int* __restrict__ idx, const float* __restrict__ hidden,
                        const float* __restrict__ emb, const float* __restrict__ attn_w,
                        const float* __restrict__ attn_b, float* __restrict__ attnW,
                        float* __restrict__ out2) {
    __shared__ float act[2048];
    __shared__ float sl[128];
    __shared__ float red[8];
    int b = blockIdx.x;
    int tid = threadIdx.x;
    int row = idx[b];
    for (int k = tid; k < 1024; k += 256) {
        act[k] = emb[(size_t)row * 1024 + k];
        act[1024 + k] = hidden[b * 1024 + k];
    }
    __syncthreads();
    int wave = tid >> 6, lane = tid & 63;
    for (int l = wave; l < 128; l += 4) {
        const float* wr = attn_w + (size_t)l * 2048;
        float s = 0.f;
        #pragma unroll 8
        for (int k = lane; k < 2048; k += 64) s += wr[k] * act[k];
        #pragma unroll
        for (int off = 32; off; off >>= 1) s += __shfl_xor(s, off);
        if (lane == 0) sl[l] = s + attn_b[l];
    }
    __syncthreads();
    float x = (tid < 128) ? sl[tid] : -1e30f;
    float m = x;
    #pragma unroll
    for (int off = 32; off; off >>= 1) m = fmaxf(m, __shfl_xor(m, off));
    if (lane == 0) red[wave] = m;
    __syncthreads();
    m = fmaxf(fmaxf(red[0], red[1]), fmaxf(red[2], red[3]));
    float e = (tid < 128) ? expf(x - m) : 0.f;
    float ssum = e;
    #pragma unroll
    for (int off = 32; off; off >>= 1) ssum += __shfl_xor(ssum, off);
    if (lane == 0) red[4 + wave] = ssum;
    __syncthreads();
    float stot = red[4] + red[5] + red[6] + red[7];
    if (tid < 128) {
        float w = e / stot;
        attnW[b * 128 + tid] = w;
        out2[b * 128 + tid] = w;
    }
}

// ---------- 3. context: ctx[b][e] = sum_l a[b][l]*enc[l][b][e] -> cat2T rows 1024.. ----------
__global__ void k_ctx(const float* __restrict__ attnW, const float* __restrict__ enc,
                      float* __restrict__ cat2T) {
    __shared__ float a[128];
    int b = blockIdx.y;
    int e = blockIdx.x * 256 + threadIdx.x;
    if (threadIdx.x < 128) a[threadIdx.x] = attnW[b * 128 + threadIdx.x];
    __syncthreads();
    float acc = 0.f;
    #pragma unroll 4
    for (int l = 0; l < 128; ++l)
        acc += a[l] * enc[((size_t)l * 64 + b) * 1024 + e];
    cat2T[(size_t)(1024 + e) * 64 + b] = acc;
}

// ---------- 4. generic Y[o][b] = W[o,:] . actT[:,b] + bias (opt relu) ----------
__global__ __launch_bounds__(256) void k_matvec(const float* __restrict__ W,
                                                const float* __restrict__ act,
                                                const float* __restrict__ bias,
                                                float* __restrict__ Y, int K, int relu) {
    int wave = threadIdx.x >> 6, lane = threadIdx.x & 63;
    int o0 = (blockIdx.x * 4 + wave) * 4;
    const float* w0 = W + (size_t)o0 * K;
    const float* w1 = w0 + K;
    const float* w2 = w1 + K;
    const float* w3 = w2 + K;
    float a0 = 0.f, a1 = 0.f, a2 = 0.f, a3 = 0.f;
    #pragma unroll 8
    for (int k = 0; k < K; ++k) {
        float a = act[k * 64 + lane];
        a0 += w0[k] * a; a1 += w1[k] * a; a2 += w2[k] * a; a3 += w3[k] * a;
    }
    float r0 = a0 + bias[o0 + 0];
    float r1 = a1 + bias[o0 + 1];
    float r2 = a2 + bias[o0 + 2];
    float r3 = a3 + bias[o0 + 3];
    if (relu) {
        r0 = fmaxf(r0, 0.f); r1 = fmaxf(r1, 0.f);
        r2 = fmaxf(r2, 0.f); r3 = fmaxf(r3, 0.f);
    }
    Y[(o0 + 0) * 64 + lane] = r0;
    Y[(o0 + 1) * 64 + lane] = r1;
    Y[(o0 + 2) * 64 + lane] = r2;
    Y[(o0 + 3) * 64 + lane] = r3;
}

// ---------- 5. GRU gates ----------
__global__ void k_gates(const float* __restrict__ giT, const float* __restrict__ ghT,
                        const float* __restrict__ h0T, float* __restrict__ out1,
                        unsigned short* __restrict__ hbf) {
    int i = blockIdx.x * 256 + threadIdx.x;  // 64*1024
    int u = i >> 6, b = i & 63;
    float ir = giT[u * 64 + b],          hr = ghT[u * 64 + b];
    float iz = giT[(1024 + u) * 64 + b], hz = ghT[(1024 + u) * 64 + b];
    float in_ = giT[(2048 + u) * 64 + b], hn = ghT[(2048 + u) * 64 + b];
    float r = 1.f / (1.f + expf(-(ir + hr)));
    float z = 1.f / (1.f + expf(-(iz + hz)));
    float n = tanhf(in_ + r * hn);
    float h = (1.f - z) * n + z * h0T[u * 64 + b];
    out1[b * 1024 + u] = h;
    // bf16 RNE
    unsigned int ub = __float_as_uint(h);
    hbf[b * 1024 + u] = (unsigned short)((ub + 0x7fffu + ((ub >> 16) & 1u)) >> 16);
}

// ---------- 6. logits[b][v] = h . out_w[v,:] + out_b[v]  (bf16 MFMA) ----------
__global__ __launch_bounds__(256) void k_gemm(const float* __restrict__ Wt,
                                              const unsigned short* __restrict__ hbf,
                                              const float* __restrict__ out_b,
                                              float* __restrict__ out0) {
    int wave = threadIdx.x >> 6, lane = threadIdx.x & 63;
    int quad = lane >> 4, r16 = lane & 15;
    int v0 = blockIdx.x * 128 + wave * 32;
    int va0 = min(v0 + r16, V - 1);
    int va1 = min(v0 + 16 + r16, V - 1);
    const float* wr0 = Wt + (size_t)va0 * 1024 + quad * 8;
    const float* wr1 = Wt + (size_t)va1 * 1024 + quad * 8;
    v4f acc[2][4] = {};
    for (int kk = 0; kk < 32; ++kk) {
        int kb = kk * 32;
        float4 pa0 = *(const float4*)(wr0 + kb);
        float4 pa1 = *(const float4*)(wr0 + kb + 4);
        float4 pb0 = *(const float4*)(wr1 + kb);
        float4 pb1 = *(const float4*)(wr1 + kb + 4);
        union { unsigned int u[4]; v8us v; } A0, A1;
        A0.u[0] = pk_bf2(pa0.x, pa0.y); A0.u[1] = pk_bf2(pa0.z, pa0.w);
        A0.u[2] = pk_bf2(pa1.x, pa1.y); A0.u[3] = pk_bf2(pa1.z, pa1.w);
        A1.u[0] = pk_bf2(pb0.x, pb0.y); A1.u[1] = pk_bf2(pb0.z, pb0.w);
        A1.u[2] = pk_bf2(pb1.x, pb1.y); A1.u[3] = pk_bf2(pb1.z, pb1.w);
        v8bf a0 = __builtin_bit_cast(v8bf, A0.v);
        v8bf a1 = __builtin_bit_cast(v8bf, A1.v);
        #pragma unroll
        for (int nt = 0; nt < 4; ++nt) {
            v8us bu = *(const v8us*)(hbf + (size_t)(nt * 16 + r16) * 1024 + kb + quad * 8);
            v8bf bf = __builtin_bit_cast(v8bf, bu);
            acc[0][nt] = __builtin_amdgcn_mfma_f32_16x16x32_bf16(a0, bf, acc[0][nt], 0, 0, 0);
            acc[1][nt] = __builtin_amdgcn_mfma_f32_16x16x32_bf16(a1, bf, acc[1][nt], 0, 0, 0);
        }
    }
    #pragma unroll
    for (int mt = 0; mt < 2; ++mt) {
        int vbase = v0 + mt * 16 + quad * 4;
        #pragma unroll
        for (int nt = 0; nt < 4; ++nt) {
            int b = nt * 16 + r16;
            #pragma unroll
            for (int r = 0; r < 4; ++r) {
                int v = vbase + r;
                if (v < V) out0[(size_t)b * V + v] = acc[mt][nt][r] + out_b[v];
            }
        }
    }
}

// ---------- 7. per-(b,chunk) online logsumexp partials ----------
__global__ void k_lse(const float* __restrict__ out0, float* __restrict__ part) {
    int b = blockIdx.y, c = blockIdx.x;
    int tid = threadIdx.x;
    const int CH = (V + 7) / 8;
    int vs = c * CH, ve = min(vs + CH, V);
    float m = -1e30f, s = 0.f;
    for (int v = vs + tid; v < ve; v += 256) {
        float x = out0[(size_t)b * V + v];
        float nm = fmaxf(m, x);
        s = s * __expf(m - nm) + __expf(x - nm);
        m = nm;
    }
    __shared__ float sm[4], ss[4];
    int lane = tid & 63, wave = tid >> 6;
    #pragma unroll
    for (int off = 32; off; off >>= 1) {
        float om = __shfl_xor(m, off), os = __shfl_xor(s, off);
        float nm = fmaxf(m, om);
        s = s * __expf(m - nm) + os * __expf(om - nm);
        m = nm;
    }
    if (lane == 0) { sm[wave] = m; ss[wave] = s; }
    __syncthreads();
    if (tid == 0) {
        float M = sm[0], S = ss[0];
        #pragma unroll
        for (int w = 1; w < 4; ++w) {
            float nm = fmaxf(M, sm[w]);
            S = S * __expf(M - nm) + ss[w] * __expf(sm[w] - nm);
            M = nm;
        }
        part[(b * 8 + c) * 2 + 0] = M;
        part[(b * 8 + c) * 2 + 1] = S;
    }
}

// ---------- 8. subtract lse in place ----------
__global__ void k_final(float* __restrict__ out0, const float* __restrict__ part) {
    int b = blockIdx.y;
    float M = part[b * 16 + 0], S = part[b * 16 + 1];
    #pragma unroll
    for (int c = 1; c < 8; ++c) {
        float m2 = part[(b * 8 + c) * 2], s2 = part[(b * 8 + c) * 2 + 1];
        float nm = fmaxf(M, m2);
        S = S * __expf(M - nm) + s2 * __expf(m2 - nm);
        M = nm;
    }
    float lse = M + __logf(S);
    int base = blockIdx.x * 2048 + threadIdx.x;
    #pragma unroll
    for (int j = 0; j < 8; ++j) {
        int v = base + j * 256;
        if (v < V) out0[(size_t)b * V + v] -= lse;
    }
}

extern "C" void kernel_launch(void* const* d_in, const int* in_sizes, int n_in,
                              void* d_out, int out_size, void* d_ws, size_t ws_size,
                              hipStream_t stream) {
    const int*   input_tensor = (const int*)d_in[0];
    const float* hidden  = (const float*)d_in[1];
    const float* enc     = (const float*)d_in[2];
    const float* emb     = (const float*)d_in[4];
    const float* attn_w  = (const float*)d_in[5];
    const float* attn_b  = (const float*)d_in[6];
    const float* comb_w  = (const float*)d_in[7];
    const float* comb_b  = (const float*)d_in[8];
    const float* w_ih    = (const float*)d_in[9];
    const float* w_hh    = (const float*)d_in[10];
    const float* b_ih    = (const float*)d_in[11];
    const float* b_hh    = (const float*)d_in[12];
    const float* out_w   = (const float*)d_in[13];
    const float* out_b   = (const float*)d_in[14];

    float* out0 = (float*)d_out;                 // [64][50257]
    float* out1 = out0 + (size_t)B * V;          // [64][1024]
    float* out2 = out1 + B * HD;                 // [64][128]

    float* ws    = (float*)d_ws;
    float* cat1T = ws;                  // 2048*64
    float* cat2T = ws + 131072;         // 2048*64
    float* attnW = ws + 262144;         // 64*128
    float* xT    = ws + 270336;         // 1024*64
    float* giT   = ws + 335872;         // 3072*64
    float* ghT   = ws + 532480;         // 3072*64
    unsigned short* hbf = (unsigned short*)(ws + 729088);  // 64*1024 bf16
    float* part  = ws + 761856;         // 64*8*2

    float* h0T = cat1T + 1024 * 64;

    k_prep<<<512, 256, 0, stream>>>(input_tensor, hidden, emb, cat1T, cat2T);
    k_attnw<<<64, 256, 0, stream>>>(input_tensor, hidden, emb, attn_w, attn_b, attnW, out2);
    k_ctx<<<dim3(4, 64), 256, 0, stream>>>(attnW, enc, cat2T);
    k_matvec<<<64, 256, 0, stream>>>(comb_w, cat2T, comb_b, xT, 2048, 1);
    k_matvec<<<192, 256, 0, stream>>>(w_ih, xT, b_ih, giT, 1024, 0);
    k_matvec<<<192, 256, 0, stream>>>(w_hh, h0T, b_hh, ghT, 1024, 0);
    k_gates<<<256, 256, 0, stream>>>(giT, ghT, h0T, out1, hbf);
    k_gemm<<<393, 256, 0, stream>>>(out_w, hbf, out_b, out0);
    k_lse<<<dim3(8, 64), 256, 0, stream>>>(out0, part);
    k_final<<<dim3(25, 64), 256, 0, stream>>>(out0, part);
}

// Round 2
// 615.669 us; speedup vs baseline: 1.3959x; 1.3959x over previous
//
#include <hip/hip_runtime.h>
#include <math.h>

#define V 50257
#define B 64
#define HD 1024
#define LSRC 128

typedef float v4f __attribute__((ext_vector_type(4)));
typedef __bf16 v8bf __attribute__((ext_vector_type(8)));
typedef unsigned short v8us __attribute__((ext_vector_type(8)));

__device__ inline unsigned int pk_bf2(float x, float y) {
    // pack two f32 to bf16x2 by truncation (low = x, high = y)
    return (__float_as_uint(x) >> 16) | (__float_as_uint(y) & 0xffff0000u);
}
__device__ inline unsigned short bf_rne(float x) {
    unsigned int u = __float_as_uint(x);
    return (unsigned short)((u + 0x7fffu + ((u >> 16) & 1u)) >> 16);
}
__device__ inline unsigned int pk2_rne(float x, float y) {
    return (unsigned int)bf_rne(x) | ((unsigned int)bf_rne(y) << 16);
}

// ---------- 1. gather embedding + h0 into b-major bf16 ----------
__global__ void k_prep(const int* __restrict__ idx, const float* __restrict__ hidden,
                       const float* __restrict__ emb, unsigned short* __restrict__ actC,
                       unsigned short* __restrict__ h0B) {
    int i = blockIdx.x * 256 + threadIdx.x;   // 64*1024
    int b = i >> 10, k = i & 1023;
    actC[b * 2048 + k] = bf_rne(emb[(size_t)idx[b] * 1024 + k]);
    h0B[b * 1024 + k] = bf_rne(hidden[b * 1024 + k]);
}

// ---------- 2. attention logits + softmax ----------
__global__ void k_attnw(const int* __restrict__ idx, const float* __restrict__ hidden,
                        const float* __restrict__ emb, const float* __restrict__ attn_w,
                        const float* __restrict__ attn_b, float* __restrict__ attnW,
                        float* __restrict__ out2) {
    __shared__ float act[2048];
    __shared__ float sl[128];
    __shared__ float red[8];
    int b = blockIdx.x;
    int tid = threadIdx.x;
    int row = idx[b];
    for (int k = tid; k < 1024; k += 256) {
        act[k] = emb[(size_t)row * 1024 + k];
        act[1024 + k] = hidden[b * 1024 + k];
    }
    __syncthreads();
    int wave = tid >> 6, lane = tid & 63;
    for (int l = wave; l < 128; l += 4) {
        const float* wr = attn_w + (size_t)l * 2048;
        float s = 0.f;
        #pragma unroll 8
        for (int k = lane; k < 2048; k += 64) s += wr[k] * act[k];
        #pragma unroll
        for (int off = 32; off; off >>= 1) s += __shfl_xor(s, off);
        if (lane == 0) sl[l] = s + attn_b[l];
    }
    __syncthreads();
    float x = (tid < 128) ? sl[tid] : -1e30f;
    float m = x;
    #pragma unroll
    for (int off = 32; off; off >>= 1) m = fmaxf(m, __shfl_xor(m, off));
    if (lane == 0) red[wave] = m;
    __syncthreads();
    m = fmaxf(fmaxf(red[0], red[1]), fmaxf(red[2], red[3]));
    float e = (tid < 128) ? expf(x - m) : 0.f;
    float ssum = e;
    #pragma unroll
    for (int off = 32; off; off >>= 1) ssum += __shfl_xor(ssum, off);
    if (lane == 0) red[4 + wave] = ssum;
    __syncthreads();
    float stot = red[4] + red[5] + red[6] + red[7];
    if (tid < 128) {
        float w = e / stot;
        attnW[b * 128 + tid] = w;
        out2[b * 128 + tid] = w;
    }
}

// ---------- 3. context -> actC[b][1024+e] (bf16) ----------
__global__ void k_ctx(const float* __restrict__ attnW, const float* __restrict__ enc,
                      unsigned short* __restrict__ actC) {
    __shared__ float a[128];
    int b = blockIdx.y;
    int e = blockIdx.x * 256 + threadIdx.x;
    if (threadIdx.x < 128) a[threadIdx.x] = attnW[b * 128 + threadIdx.x];
    __syncthreads();
    float acc = 0.f;
    #pragma unroll 4
    for (int l = 0; l < 128; ++l)
        acc += a[l] * enc[((size_t)l * 64 + b) * 1024 + e];
    actC[b * 2048 + 1024 + e] = bf_rne(acc);
}

// ---------- 4. split-K MFMA GEMM: P[ks][b][m] += W[m,:].actB[b,:] over k-chunk ----------
__global__ __launch_bounds__(256) void k_mm(const float* __restrict__ W,
                                            const unsigned short* __restrict__ actB,
                                            float* __restrict__ P, int M, int K, int Kc) {
    int wave = threadIdx.x >> 6, lane = threadIdx.x & 63;
    int quad = lane >> 4, r16 = lane & 15;
    int row0 = blockIdx.x * 64 + wave * 16;
    int kbase = blockIdx.y * Kc;
    const float* wr = W + (size_t)(row0 + r16) * K + kbase + quad * 8;
    const unsigned short* ab = actB + kbase + quad * 8;
    v4f acc[4] = {};
    for (int kk = 0; kk < Kc; kk += 32) {
        float4 p0 = *(const float4*)(wr + kk);
        float4 p1 = *(const float4*)(wr + kk + 4);
        union { unsigned int u[4]; v8us v; } A;
        A.u[0] = pk2_rne(p0.x, p0.y); A.u[1] = pk2_rne(p0.z, p0.w);
        A.u[2] = pk2_rne(p1.x, p1.y); A.u[3] = pk2_rne(p1.z, p1.w);
        v8bf af = __builtin_bit_cast(v8bf, A.v);
        #pragma unroll
        for (int nt = 0; nt < 4; ++nt) {
            v8us bu = *(const v8us*)(ab + (size_t)(nt * 16 + r16) * K + kk);
            v8bf bf = __builtin_bit_cast(v8bf, bu);
            acc[nt] = __builtin_amdgcn_mfma_f32_16x16x32_bf16(af, bf, acc[nt], 0, 0, 0);
        }
    }
    float* po = P + (size_t)blockIdx.y * 64 * M;
    #pragma unroll
    for (int nt = 0; nt < 4; ++nt) {
        int b = nt * 16 + r16;
        float4 val = make_float4(acc[nt][0], acc[nt][1], acc[nt][2], acc[nt][3]);
        *(float4*)(po + (size_t)b * M + row0 + quad * 4) = val;
    }
}

// ---------- 5. reduce comb partials + bias + relu -> xB bf16 ----------
__global__ void k_redc(const float* __restrict__ Pc, const float* __restrict__ comb_b,
                       unsigned short* __restrict__ xB) {
    int i = blockIdx.x * 256 + threadIdx.x;  // 64*1024
    int b = i >> 10, k = i & 1023;
    float s = comb_b[k];
    #pragma unroll
    for (int ss = 0; ss < 4; ++ss) s += Pc[((size_t)ss * 64 + b) * 1024 + k];
    s = fmaxf(s, 0.f);
    xB[b * 1024 + k] = bf_rne(s);
}

// ---------- 6. GRU gates (folds split-K reduction of gi/gh) ----------
__global__ void k_gates(const float* __restrict__ Pi, const float* __restrict__ Ph,
                        const float* __restrict__ b_ih, const float* __restrict__ b_hh,
                        const float* __restrict__ hidden, float* __restrict__ out1,
                        unsigned short* __restrict__ hbf) {
    int i = blockIdx.x * 256 + threadIdx.x;  // 64*1024
    int b = i >> 10, u = i & 1023;
    float ir = b_ih[u], iz = b_ih[1024 + u], in_ = b_ih[2048 + u];
    float hr = b_hh[u], hz = b_hh[1024 + u], hn = b_hh[2048 + u];
    #pragma unroll
    for (int s = 0; s < 4; ++s) {
        const float* pi = Pi + ((size_t)s * 64 + b) * 3072;
        const float* ph = Ph + ((size_t)s * 64 + b) * 3072;
        ir += pi[u]; iz += pi[1024 + u]; in_ += pi[2048 + u];
        hr += ph[u]; hz += ph[1024 + u]; hn += ph[2048 + u];
    }
    float r = 1.f / (1.f + __expf(-(ir + hr)));
    float z = 1.f / (1.f + __expf(-(iz + hz)));
    float n = tanhf(in_ + r * hn);
    float h0 = hidden[b * 1024 + u];
    float h = (1.f - z) * n + z * h0;
    out1[b * 1024 + u] = h;
    hbf[b * 1024 + u] = bf_rne(h);
}

// ---------- 7. logits[b][v] = h . out_w[v,:] + out_b[v]  (bf16 MFMA) ----------
__global__ __launch_bounds__(256) void k_gemm(const float* __restrict__ Wt,
                                              const unsigned short* __restrict__ hbf,
                                              const float* __restrict__ out_b,
                                              float* __restrict__ out0) {
    int wave = threadIdx.x >> 6, lane = threadIdx.x & 63;
    int quad = lane >> 4, r16 = lane & 15;
    int v0 = blockIdx.x * 128 + wave * 32;
    int va0 = min(v0 + r16, V - 1);
    int va1 = min(v0 + 16 + r16, V - 1);
    const float* wr0 = Wt + (size_t)va0 * 1024 + quad * 8;
    const float* wr1 = Wt + (size_t)va1 * 1024 + quad * 8;
    v4f acc[2][4] = {};
    for (int kk = 0; kk < 32; ++kk) {
        int kb = kk * 32;
        float4 pa0 = *(const float4*)(wr0 + kb);
        float4 pa1 = *(const float4*)(wr0 + kb + 4);
        float4 pb0 = *(const float4*)(wr1 + kb);
        float4 pb1 = *(const float4*)(wr1 + kb + 4);
        union { unsigned int u[4]; v8us v; } A0, A1;
        A0.u[0] = pk_bf2(pa0.x, pa0.y); A0.u[1] = pk_bf2(pa0.z, pa0.w);
        A0.u[2] = pk_bf2(pa1.x, pa1.y); A0.u[3] = pk_bf2(pa1.z, pa1.w);
        A1.u[0] = pk_bf2(pb0.x, pb0.y); A1.u[1] = pk_bf2(pb0.z, pb0.w);
        A1.u[2] = pk_bf2(pb1.x, pb1.y); A1.u[3] = pk_bf2(pb1.z, pb1.w);
        v8bf a0 = __builtin_bit_cast(v8bf, A0.v);
        v8bf a1 = __builtin_bit_cast(v8bf, A1.v);
        #pragma unroll
        for (int nt = 0; nt < 4; ++nt) {
            v8us bu = *(const v8us*)(hbf + (size_t)(nt * 16 + r16) * 1024 + kb + quad * 8);
            v8bf bf = __builtin_bit_cast(v8bf, bu);
            acc[0][nt] = __builtin_amdgcn_mfma_f32_16x16x32_bf16(a0, bf, acc[0][nt], 0, 0, 0);
            acc[1][nt] = __builtin_amdgcn_mfma_f32_16x16x32_bf16(a1, bf, acc[1][nt], 0, 0, 0);
        }
    }
    #pragma unroll
    for (int mt = 0; mt < 2; ++mt) {
        int vbase = v0 + mt * 16 + quad * 4;
        #pragma unroll
        for (int nt = 0; nt < 4; ++nt) {
            int b = nt * 16 + r16;
            #pragma unroll
            for (int r = 0; r < 4; ++r) {
                int v = vbase + r;
                if (v < V) out0[(size_t)b * V + v] = acc[mt][nt][r] + out_b[v];
            }
        }
    }
}

// ---------- 8. per-(b,chunk) online logsumexp partials ----------
__global__ void k_lse(const float* __restrict__ out0, float* __restrict__ part) {
    int b = blockIdx.y, c = blockIdx.x;
    int tid = threadIdx.x;
    const int CH = (V + 7) / 8;
    int vs = c * CH, ve = min(vs + CH, V);
    float m = -1e30f, s = 0.f;
    for (int v = vs + tid; v < ve; v += 256) {
        float x = out0[(size_t)b * V + v];
        float nm = fmaxf(m, x);
        s = s * __expf(m - nm) + __expf(x - nm);
        m = nm;
    }
    __shared__ float sm[4], ss[4];
    int lane = tid & 63, wave = tid >> 6;
    #pragma unroll
    for (int off = 32; off; off >>= 1) {
        float om = __shfl_xor(m, off), os = __shfl_xor(s, off);
        float nm = fmaxf(m, om);
        s = s * __expf(m - nm) + os * __expf(om - nm);
        m = nm;
    }
    if (lane == 0) { sm[wave] = m; ss[wave] = s; }
    __syncthreads();
    if (tid == 0) {
        float M = sm[0], S = ss[0];
        #pragma unroll
        for (int w = 1; w < 4; ++w) {
            float nm = fmaxf(M, sm[w]);
            S = S * __expf(M - nm) + ss[w] * __expf(sm[w] - nm);
            M = nm;
        }
        part[(b * 8 + c) * 2 + 0] = M;
        part[(b * 8 + c) * 2 + 1] = S;
    }
}

// ---------- 9. subtract lse in place ----------
__global__ void k_final(float* __restrict__ out0, const float* __restrict__ part) {
    int b = blockIdx.y;
    float M = part[b * 16 + 0], S = part[b * 16 + 1];
    #pragma unroll
    for (int c = 1; c < 8; ++c) {
        float m2 = part[(b * 8 + c) * 2], s2 = part[(b * 8 + c) * 2 + 1];
        float nm = fmaxf(M, m2);
        S = S * __expf(M - nm) + s2 * __expf(m2 - nm);
        M = nm;
    }
    float lse = M + __logf(S);
    int base = blockIdx.x * 2048 + threadIdx.x;
    #pragma unroll
    for (int j = 0; j < 8; ++j) {
        int v = base + j * 256;
        if (v < V) out0[(size_t)b * V + v] -= lse;
    }
}

extern "C" void kernel_launch(void* const* d_in, const int* in_sizes, int n_in,
                              void* d_out, int out_size, void* d_ws, size_t ws_size,
                              hipStream_t stream) {
    const int*   input_tensor = (const int*)d_in[0];
    const float* hidden  = (const float*)d_in[1];
    const float* enc     = (const float*)d_in[2];
    const float* emb     = (const float*)d_in[4];
    const float* attn_w  = (const float*)d_in[5];
    const float* attn_b  = (const float*)d_in[6];
    const float* comb_w  = (const float*)d_in[7];
    const float* comb_b  = (const float*)d_in[8];
    const float* w_ih    = (const float*)d_in[9];
    const float* w_hh    = (const float*)d_in[10];
    const float* b_ih    = (const float*)d_in[11];
    const float* b_hh    = (const float*)d_in[12];
    const float* out_w   = (const float*)d_in[13];
    const float* out_b   = (const float*)d_in[14];

    float* out0 = (float*)d_out;                 // [64][50257]
    float* out1 = out0 + (size_t)B * V;          // [64][1024]
    float* out2 = out1 + B * HD;                 // [64][128]

    float* ws    = (float*)d_ws;
    float* attnW = ws;                                   // 8192 f
    float* part  = ws + 8192;                            // 1024 f
    float* Pc    = ws + 9216;                            // 4*64*1024 f
    unsigned short* actC = (unsigned short*)(ws + 271360);  // 64*2048 bf16
    unsigned short* h0B  = (unsigned short*)(ws + 336896);  // 64*1024 bf16
    unsigned short* xB   = (unsigned short*)(ws + 369664);  // 64*1024 bf16
    unsigned short* hbf  = (unsigned short*)(ws + 402432);  // 64*1024 bf16

    // gi/gh split-K partials parked in the not-yet-written logits region of d_out
    float* Pi = out0;                      // 4*64*3072 f
    float* Ph = out0 + 4 * 64 * 3072;      // 4*64*3072 f

    k_prep<<<256, 256, 0, stream>>>(input_tensor, hidden, emb, actC, h0B);
    k_attnw<<<64, 256, 0, stream>>>(input_tensor, hidden, emb, attn_w, attn_b, attnW, out2);
    k_ctx<<<dim3(4, 64), 256, 0, stream>>>(attnW, enc, actC);
    k_mm<<<dim3(16, 4), 256, 0, stream>>>(comb_w, actC, Pc, 1024, 2048, 512);
    k_mm<<<dim3(48, 4), 256, 0, stream>>>(w_hh, h0B, Ph, 3072, 1024, 256);
    k_redc<<<256, 256, 0, stream>>>(Pc, comb_b, xB);
    k_mm<<<dim3(48, 4), 256, 0, stream>>>(w_ih, xB, Pi, 3072, 1024, 256);
    k_gates<<<256, 256, 0, stream>>>(Pi, Ph, b_ih, b_hh, hidden, out1, hbf);
    k_gemm<<<393, 256, 0, stream>>>(out_w, hbf, out_b, out0);
    k_lse<<<dim3(8, 64), 256, 0, stream>>>(out0, part);
    k_final<<<dim3(25, 64), 256, 0, stream>>>(out0, part);
}

// Round 4
// 541.255 us; speedup vs baseline: 1.5878x; 1.1375x over previous
//
#include <hip/hip_runtime.h>
#include <math.h>

#define V 50257
#define B 64
#define HD 1024
#define LSRC 128
#define NBLK 786   // k_gemm blocks: 786*64 = 50304 >= V

typedef float v4f __attribute__((ext_vector_type(4)));
typedef __bf16 v8bf __attribute__((ext_vector_type(8)));
typedef unsigned short v8us __attribute__((ext_vector_type(8)));

__device__ inline unsigned short bf_rne(float x) {
    unsigned int u = __float_as_uint(x);
    return (unsigned short)((u + 0x7fffu + ((u >> 16) & 1u)) >> 16);
}
__device__ inline unsigned int pk2_rne(float x, float y) {
    return (unsigned int)bf_rne(x) | ((unsigned int)bf_rne(y) << 16);
}

// ---------- 1. gather emb + h0 -> catB (b-major, [emb|h0]); actC emb half ----------
__global__ void k_prep(const int* __restrict__ idx, const float* __restrict__ hidden,
                       const float* __restrict__ emb, unsigned short* __restrict__ catB,
                       unsigned short* __restrict__ actC) {
    int i = blockIdx.x * 256 + threadIdx.x;   // 64*2048
    int b = i >> 11, k = i & 2047;
    unsigned short v;
    if (k < 1024) {
        v = bf_rne(emb[(size_t)idx[b] * 1024 + k]);
        actC[b * 2048 + k] = v;
    } else {
        v = bf_rne(hidden[b * 1024 + (k - 1024)]);
    }
    catB[b * 2048 + k] = v;
}

// ---------- split-K MFMA GEMM core: P[ks][b][M] = W[rows,:k-chunk] . act ----------
__device__ __forceinline__ void mm_core(const float* __restrict__ W,
                                        const unsigned short* __restrict__ act, int as_,
                                        float* __restrict__ P, int M, int K, int Kc,
                                        int mx, int ks, int tid) {
    int wave = tid >> 6, lane = tid & 63;
    int quad = lane >> 4, r16 = lane & 15;
    int row0 = mx * 64 + wave * 16;
    int kbase = ks * Kc;
    const float* wr = W + (size_t)(row0 + r16) * K + kbase + quad * 8;
    const unsigned short* ab = act + kbase + quad * 8;
    v4f acc[4] = {};
    for (int kk = 0; kk < Kc; kk += 32) {
        float4 p0 = *(const float4*)(wr + kk);
        float4 p1 = *(const float4*)(wr + kk + 4);
        union { unsigned int u[4]; v8us v; } A;
        A.u[0] = pk2_rne(p0.x, p0.y); A.u[1] = pk2_rne(p0.z, p0.w);
        A.u[2] = pk2_rne(p1.x, p1.y); A.u[3] = pk2_rne(p1.z, p1.w);
        v8bf af = __builtin_bit_cast(v8bf, A.v);
        #pragma unroll
        for (int nt = 0; nt < 4; ++nt) {
            v8us bu = *(const v8us*)(ab + (size_t)(nt * 16 + r16) * as_ + kk);
            v8bf bf = __builtin_bit_cast(v8bf, bu);
            acc[nt] = __builtin_amdgcn_mfma_f32_16x16x32_bf16(af, bf, acc[nt], 0, 0, 0);
        }
    }
    float* po = P + (size_t)ks * 64 * M;
    #pragma unroll
    for (int nt = 0; nt < 4; ++nt) {
        int b = nt * 16 + r16;
        float4 val = make_float4(acc[nt][0], acc[nt][1], acc[nt][2], acc[nt][3]);
        *(float4*)(po + (size_t)b * M + row0 + quad * 4) = val;
    }
}

__global__ __launch_bounds__(256) void k_mm(const float* __restrict__ W,
                                            const unsigned short* __restrict__ act,
                                            float* __restrict__ P, int M, int K, int Kc,
                                            int as_) {
    mm_core(W, act, as_, P, M, K, Kc, blockIdx.x, blockIdx.y, threadIdx.x);
}

// fused: comb GEMM (bx<16) + w_hh GEMM (bx>=16)
__global__ __launch_bounds__(256) void k_mm2(const float* __restrict__ Wc,
                                             const unsigned short* __restrict__ actC,
                                             float* __restrict__ Pc,
                                             const float* __restrict__ Wh,
                                             const unsigned short* __restrict__ h0B,
                                             float* __restrict__ Ph) {
    int bx = blockIdx.x;
    if (bx < 16) mm_core(Wc, actC, 2048, Pc, 1024, 2048, 512, bx, blockIdx.y, threadIdx.x);
    else         mm_core(Wh, h0B, 2048, Ph, 3072, 1024, 256, bx - 16, blockIdx.y, threadIdx.x);
}

// ---------- 3. softmax(attn partials) + context -> actC[b][1024+e]; out2 ----------
__global__ void k_ctxs(const float* __restrict__ Pa, const float* __restrict__ attn_b,
                       const float* __restrict__ enc, unsigned short* __restrict__ actC,
                       float* __restrict__ out2) {
    __shared__ float a_sh[128];
    __shared__ float red[8];
    int b = blockIdx.y, tid = threadIdx.x;
    int lane = tid & 63, wave = tid >> 6;
    float x = -1e30f;
    if (tid < 128) {
        x = attn_b[tid];
        #pragma unroll
        for (int ks = 0; ks < 4; ++ks) x += Pa[(ks * 64 + b) * 128 + tid];
    }
    float m = x;
    #pragma unroll
    for (int off = 32; off; off >>= 1) m = fmaxf(m, __shfl_xor(m, off));
    if (lane == 0) red[wave] = m;
    __syncthreads();
    m = fmaxf(fmaxf(red[0], red[1]), fmaxf(red[2], red[3]));
    float e = (tid < 128) ? __expf(x - m) : 0.f;
    float ssum = e;
    #pragma unroll
    for (int off = 32; off; off >>= 1) ssum += __shfl_xor(ssum, off);
    if (lane == 0) red[4 + wave] = ssum;
    __syncthreads();
    float stot = red[4] + red[5] + red[6] + red[7];
    if (tid < 128) {
        float w = e / stot;
        a_sh[tid] = w;
        if (blockIdx.x == 0) out2[b * 128 + tid] = w;
    }
    __syncthreads();
    int e0 = blockIdx.x * 256 + tid;
    float acc0 = 0.f, acc1 = 0.f;
    #pragma unroll 8
    for (int l = 0; l < 128; l += 2) {
        acc0 += a_sh[l]     * enc[((size_t)(l * 64) + b) * 1024 + e0];
        acc1 += a_sh[l + 1] * enc[((size_t)((l + 1) * 64) + b) * 1024 + e0];
    }
    actC[b * 2048 + 1024 + e0] = bf_rne(acc0 + acc1);
}

// ---------- 5. reduce comb partials + bias + relu -> xB bf16 ----------
__global__ void k_redc(const float* __restrict__ Pc, const float* __restrict__ comb_b,
                       unsigned short* __restrict__ xB) {
    int i = blockIdx.x * 256 + threadIdx.x;  // 64*1024
    int b = i >> 10, k = i & 1023;
    float s = comb_b[k];
    #pragma unroll
    for (int ss = 0; ss < 4; ++ss) s += Pc[((size_t)ss * 64 + b) * 1024 + k];
    s = fmaxf(s, 0.f);
    xB[b * 1024 + k] = bf_rne(s);
}

// ---------- 6. GRU gates (folds split-K reduction of gi/gh) ----------
__global__ void k_gates(const float* __restrict__ Pi, const float* __restrict__ Ph,
                        const float* __restrict__ b_ih, const float* __restrict__ b_hh,
                        const float* __restrict__ hidden, float* __restrict__ out1,
                        unsigned short* __restrict__ hbf) {
    int i = blockIdx.x * 256 + threadIdx.x;  // 64*1024
    int b = i >> 10, u = i & 1023;
    float ir = b_ih[u], iz = b_ih[1024 + u], in_ = b_ih[2048 + u];
    float hr = b_hh[u], hz = b_hh[1024 + u], hn = b_hh[2048 + u];
    #pragma unroll
    for (int s = 0; s < 4; ++s) {
        const float* pi = Pi + ((size_t)s * 64 + b) * 3072;
        const float* ph = Ph + ((size_t)s * 64 + b) * 3072;
        ir += pi[u]; iz += pi[1024 + u]; in_ += pi[2048 + u];
        hr += ph[u]; hz += ph[1024 + u]; hn += ph[2048 + u];
    }
    float r = 1.f / (1.f + __expf(-(ir + hr)));
    float z = 1.f / (1.f + __expf(-(iz + hz)));
    float n = tanhf(in_ + r * hn);
    float h0 = hidden[b * 1024 + u];
    float h = (1.f - z) * n + z * h0;
    out1[b * 1024 + u] = h;
    hbf[b * 1024 + u] = bf_rne(h);
}

// ---------- 7. logits + bias + per-block online LSE partials ----------
__global__ __launch_bounds__(256) void k_gemm(const float* __restrict__ Wt,
                                              const unsigned short* __restrict__ hbf,
                                              const float* __restrict__ out_b,
                                              float* __restrict__ out0,
                                              float* __restrict__ m_part,
                                              float* __restrict__ s_part) {
    __shared__ float sm[4][64], ss[4][64];
    int tid = threadIdx.x;
    int wave = tid >> 6, lane = tid & 63;
    int quad = lane >> 4, r16 = lane & 15;
    int v0 = blockIdx.x * 64 + wave * 16;
    int va = min(v0 + r16, V - 1);
    const float* wr = Wt + (size_t)va * 1024 + quad * 8;
    const unsigned short* ab = hbf + quad * 8;
    v4f acc[4] = {};
    for (int kk = 0; kk < 1024; kk += 32) {
        float4 p0 = *(const float4*)(wr + kk);
        float4 p1 = *(const float4*)(wr + kk + 4);
        union { unsigned int u[4]; v8us v; } A;
        A.u[0] = pk2_rne(p0.x, p0.y); A.u[1] = pk2_rne(p0.z, p0.w);
        A.u[2] = pk2_rne(p1.x, p1.y); A.u[3] = pk2_rne(p1.z, p1.w);
        v8bf af = __builtin_bit_cast(v8bf, A.v);
        #pragma unroll
        for (int nt = 0; nt < 4; ++nt) {
            v8us bu = *(const v8us*)(ab + (size_t)(nt * 16 + r16) * 1024 + kk);
            v8bf bf = __builtin_bit_cast(v8bf, bu);
            acc[nt] = __builtin_amdgcn_mfma_f32_16x16x32_bf16(af, bf, acc[nt], 0, 0, 0);
        }
    }
    #pragma unroll
    for (int nt = 0; nt < 4; ++nt) {
        int b = nt * 16 + r16;
        float lm = -1e30f, lsum = 0.f;
        #pragma unroll
        for (int r = 0; r < 4; ++r) {
            int v = v0 + quad * 4 + r;
            if (v < V) {
                float x = acc[nt][r] + out_b[v];
                out0[(size_t)b * V + v] = x;
                float nm = fmaxf(lm, x);
                lsum = lsum * __expf(lm - nm) + __expf(x - nm);
                lm = nm;
            }
        }
        #pragma unroll
        for (int off = 16; off <= 32; off <<= 1) {
            float om = __shfl_xor(lm, off), os = __shfl_xor(lsum, off);
            float nm = fmaxf(lm, om);
            lsum = lsum * __expf(lm - nm) + os * __expf(om - nm);
            lm = nm;
        }
        if (quad == 0) { sm[wave][b] = lm; ss[wave][b] = lsum; }
    }
    __syncthreads();
    if (tid < 64) {
        float M2 = sm[0][tid], S2 = ss[0][tid];
        #pragma unroll
        for (int w = 1; w < 4; ++w) {
            float nm = fmaxf(M2, sm[w][tid]);
            S2 = S2 * __expf(M2 - nm) + ss[w][tid] * __expf(sm[w][tid] - nm);
            M2 = nm;
        }
        m_part[(size_t)tid * NBLK + blockIdx.x] = M2;
        s_part[(size_t)tid * NBLK + blockIdx.x] = S2;
    }
}

// ---------- 8. combine per-block partials -> lse[b] ----------
__global__ void k_comb(const float* __restrict__ m_part, const float* __restrict__ s_part,
                       float* __restrict__ lse) {
    __shared__ float sm[4], ss[4];
    int b = blockIdx.x, tid = threadIdx.x;
    int lane = tid & 63, wave = tid >> 6;
    float m = -1e30f, s = 0.f;
    for (int i = tid; i < NBLK; i += 256) {
        float om = m_part[(size_t)b * NBLK + i], os = s_part[(size_t)b * NBLK + i];
        float nm = fmaxf(m, om);
        s = s * __expf(m - nm) + os * __expf(om - nm);
        m = nm;
    }
    #pragma unroll
    for (int off = 32; off; off >>= 1) {
        float om = __shfl_xor(m, off), os = __shfl_xor(s, off);
        float nm = fmaxf(m, om);
        s = s * __expf(m - nm) + os * __expf(om - nm);
        m = nm;
    }
    if (lane == 0) { sm[wave] = m; ss[wave] = s; }
    __syncthreads();
    if (tid == 0) {
        float M = sm[0], S = ss[0];
        #pragma unroll
        for (int w = 1; w < 4; ++w) {
            float nm = fmaxf(M, sm[w]);
            S = S * __expf(M - nm) + ss[w] * __expf(sm[w] - nm);
            M = nm;
        }
        lse[b] = M + __logf(S);
    }
}

// ---------- 9. subtract lse in place ----------
__global__ void k_final(float* __restrict__ out0, const float* __restrict__ lse) {
    int b = blockIdx.y;
    float l = lse[b];
    int base = blockIdx.x * 2048 + threadIdx.x;
    #pragma unroll
    for (int j = 0; j < 8; ++j) {
        int v = base + j * 256;
        if (v < V) out0[(size_t)b * V + v] -= l;
    }
}

extern "C" void kernel_launch(void* const* d_in, const int* in_sizes, int n_in,
                              void* d_out, int out_size, void* d_ws, size_t ws_size,
                              hipStream_t stream) {
    const int*   input_tensor = (const int*)d_in[0];
    const float* hidden  = (const float*)d_in[1];
    const float* enc     = (const float*)d_in[2];
    const float* emb     = (const float*)d_in[4];
    const float* attn_w  = (const float*)d_in[5];
    const float* attn_b  = (const float*)d_in[6];
    const float* comb_w  = (const float*)d_in[7];
    const float* comb_b  = (const float*)d_in[8];
    const float* w_ih    = (const float*)d_in[9];
    const float* w_hh    = (const float*)d_in[10];
    const float* b_ih    = (const float*)d_in[11];
    const float* b_hh    = (const float*)d_in[12];
    const float* out_w   = (const float*)d_in[13];
    const float* out_b   = (const float*)d_in[14];

    float* out0 = (float*)d_out;                 // [64][50257]
    float* out1 = out0 + (size_t)B * V;          // [64][1024]
    float* out2 = out1 + B * HD;                 // [64][128]

    // ws layout (float offsets); NB: 64*2048 bf16 = 131072 ushorts = 65536 floats
    float* ws = (float*)d_ws;
    float* Pa     = ws;                      // [0, 32768)        4*64*128
    float* Pc     = ws + 32768;              // [32768, 294912)   4*64*1024
    float* lse    = ws + 294912;             // [294912, 294976)  64
    float* m_part = ws + 294976;             // [294976, 345280)  64*786
    float* s_part = ws + 345280;             // [345280, 395584)  64*786
    unsigned short* catB = (unsigned short*)(ws + 395584);  // [395584, 461120)  64*2048 bf16
    unsigned short* actC = (unsigned short*)(ws + 461120);  // [461120, 526656)  64*2048 bf16
    unsigned short* xB   = (unsigned short*)(ws + 526656);  // [526656, 543040)  64*1024 bf16
    unsigned short* hbf  = (unsigned short*)(ws + 543040);  // [543040, 559424)  64*1024 bf16

    // gi/gh split-K partials parked in the not-yet-written logits region of d_out
    float* Pi = out0;                      // 4*64*3072 f
    float* Ph = out0 + 4 * 64 * 3072;      // 4*64*3072 f

    k_prep<<<512, 256, 0, stream>>>(input_tensor, hidden, emb, catB, actC);
    k_mm<<<dim3(2, 4), 256, 0, stream>>>(attn_w, catB, Pa, 128, 2048, 512, 2048);
    k_ctxs<<<dim3(4, 64), 256, 0, stream>>>(Pa, attn_b, enc, actC, out2);
    k_mm2<<<dim3(64, 4), 256, 0, stream>>>(comb_w, actC, Pc, w_hh, catB + 1024, Ph);
    k_redc<<<256, 256, 0, stream>>>(Pc, comb_b, xB);
    k_mm<<<dim3(48, 4), 256, 0, stream>>>(w_ih, xB, Pi, 3072, 1024, 256, 1024);
    k_gates<<<256, 256, 0, stream>>>(Pi, Ph, b_ih, b_hh, hidden, out1, hbf);
    k_gemm<<<NBLK, 256, 0, stream>>>(out_w, hbf, out_b, out0, m_part, s_part);
    k_comb<<<64, 256, 0, stream>>>(m_part, s_part, lse);
    k_final<<<dim3(25, 64), 256, 0, stream>>>(out0, lse);
}